// Round 1
// baseline (23886.003 us; speedup 1.0000x reference)
//
#include <hip/hip_runtime.h>
#include <math.h>

#define NROWS 2048
#define KNEI  8
#define LSEQ  64
#define HD    512
#define HD4   128
#define LATD  128
#define NHPN  4
#define NNUC  5

__device__ __forceinline__ float sigf(float x){ return 1.0f/(1.0f+__expf(-x)); }
__device__ __forceinline__ void fma4(float4& a, float s, float4 w){
  a.x = fmaf(s,w.x,a.x); a.y = fmaf(s,w.y,a.y); a.z = fmaf(s,w.z,a.z); a.w = fmaf(s,w.w,a.w);
}
__device__ __forceinline__ void add4(float4& a, float4 b){ a.x+=b.x; a.y+=b.y; a.z+=b.z; a.w+=b.w; }
__device__ __forceinline__ float4 sig4(float4 v){ return make_float4(sigf(v.x),sigf(v.y),sigf(v.z),sigf(v.w)); }
__device__ __forceinline__ float4 relu4(float4 v){ return make_float4(fmaxf(v.x,0.f),fmaxf(v.y,0.f),fmaxf(v.z,0.f),fmaxf(v.w,0.f)); }
__device__ __forceinline__ float dot4(float4 a, float4 b){ return a.x*b.x + a.y*b.y + a.z*b.z + a.w*b.w; }
__device__ __forceinline__ float4 gate_mul(float4 tv, float4 e){
  return make_float4(sigf(tv.x)*e.x, sigf(tv.y)*e.y, sigf(tv.z)*e.z, sigf(tv.w)*e.w);
}
__device__ __forceinline__ float4 gru_out(float4 z, float4 hprev, float4 pre){
  return make_float4((1.f-z.x)*hprev.x + z.x*tanhf(pre.x),
                     (1.f-z.y)*hprev.y + z.y*tanhf(pre.y),
                     (1.f-z.z)*hprev.z + z.z*tanhf(pre.z),
                     (1.f-z.w)*hprev.w + z.w*tanhf(pre.w));
}

// dst[h*HD + o] = src[o*src_cols + col_off + h]  for o<HD, h<nh
__global__ void transpose_w(const float* __restrict__ src, float* __restrict__ dst,
                            int src_cols, int col_off, int nh){
  int idx = blockIdx.x*256 + threadIdx.x;
  if (idx >= nh*HD) return;
  int h = idx / HD, o = idx - h*HD;
  dst[idx] = src[o*src_cols + col_off + h];
}

// GraphGRU message pass + topo/stop head. Block = 8 rows, 512 threads.
// Thread map: wave wv handles rows r0=(wv>>1)*2, r0+1 ; o-half = wv&1 ; 4 outputs (float4) per thread.
__global__ __launch_bounds__(512) void graphgru_k(
    const int* __restrict__ hpn_idx, const float* __restrict__ h_nei,
    const float* __restrict__ wt_z, const float* __restrict__ wx_z, const float* __restrict__ bz,
    const float* __restrict__ wx_r, const float* __restrict__ br,
    const float* __restrict__ wt_ur,
    const float* __restrict__ wt_h, const float* __restrict__ wx_h, const float* __restrict__ bh,
    const float* __restrict__ wt_topo, const float* __restrict__ b_topo_nl,
    const float* __restrict__ w_topo, const float* __restrict__ b_topo,
    float* __restrict__ msg, float* __restrict__ out_stop)
{
  __shared__ float sumh[8][HD];
  __shared__ float hk[8][HD];
  __shared__ float sg[8][HD];
  __shared__ float red[8][2];
  const int t = threadIdx.x, lane = t&63, wv = t>>6;
  const int r0 = (wv>>1)<<1;
  const int oh = wv&1;
  const int ob4 = 64*oh + lane;
  const int n0 = blockIdx.x*8;
  float4* sumh4 = (float4*)(&sumh[0][0]);
  float4* hk4   = (float4*)(&hk[0][0]);
  float4* sg4   = (float4*)(&sg[0][0]);
  const float4* hn4 = (const float4*)h_nei;

  // sum over K neighbors
  for (int idx=t; idx<8*HD4; idx+=512){
    int r = idx>>7, c = idx&127;
    size_t base = ((size_t)(n0+r))*KNEI*HD4 + c;
    float4 s = hn4[base];
    #pragma unroll
    for (int k=1;k<KNEI;++k) add4(s, hn4[base + (size_t)k*HD4]);
    sumh4[idx] = s;
  }
  __syncthreads();

  const int hp0 = hpn_idx[n0+r0], hp1 = hpn_idx[n0+r0+1];
  const float4* bz4 = (const float4*)bz;
  const float4* wxz4 = (const float4*)wx_z;
  const float4* wtz4 = (const float4*)wt_z;
  // z gate
  float4 z0 = bz4[ob4]; add4(z0, wxz4[hp0*HD4 + ob4]);
  float4 z1 = bz4[ob4]; add4(z1, wxz4[hp1*HD4 + ob4]);
  for (int h=0;h<HD;++h){
    float a0 = sumh[r0][h], a1 = sumh[r0+1][h];
    float4 w = wtz4[h*HD4 + ob4];
    fma4(z0,a0,w); fma4(z1,a1,w);
  }
  z0 = sig4(z0); z1 = sig4(z1);

  // r gates per neighbor, accumulate sum_gated
  const float4* br4 = (const float4*)br;
  const float4* wxr4 = (const float4*)wx_r;
  const float4* wtur4 = (const float4*)wt_ur;
  float4 rb0 = br4[ob4]; add4(rb0, wxr4[hp0*HD4 + ob4]);
  float4 rb1 = br4[ob4]; add4(rb1, wxr4[hp1*HD4 + ob4]);
  float4 sg0 = make_float4(0.f,0.f,0.f,0.f), sg1 = sg0;
  for (int k=0;k<KNEI;++k){
    __syncthreads();
    for (int idx=t; idx<8*HD4; idx+=512){
      int r = idx>>7, c = idx&127;
      hk4[idx] = hn4[((size_t)(n0+r)*KNEI + (size_t)k)*HD4 + c];
    }
    __syncthreads();
    float4 t0 = rb0, t1 = rb1;
    for (int h=0;h<HD;++h){
      float a0 = hk[r0][h], a1 = hk[r0+1][h];
      float4 w = wtur4[h*HD4 + ob4];
      fma4(t0,a0,w); fma4(t1,a1,w);
    }
    float4 e0 = hk4[r0*HD4 + ob4], e1 = hk4[(r0+1)*HD4 + ob4];
    add4(sg0, gate_mul(t0, e0));
    add4(sg1, gate_mul(t1, e1));
  }
  __syncthreads();
  sg4[r0*HD4+ob4] = sg0; sg4[(r0+1)*HD4+ob4] = sg1;
  __syncthreads();

  // pre_h
  const float4* bh4 = (const float4*)bh;
  const float4* wxh4 = (const float4*)wx_h;
  const float4* wth4 = (const float4*)wt_h;
  float4 p0 = bh4[ob4]; add4(p0, wxh4[hp0*HD4+ob4]);
  float4 p1 = bh4[ob4]; add4(p1, wxh4[hp1*HD4+ob4]);
  for (int h=0;h<HD;++h){
    float a0 = sg[r0][h], a1 = sg[r0+1][h];
    float4 w = wth4[h*HD4+ob4];
    fma4(p0,a0,w); fma4(p1,a1,w);
  }
  float4 sh0 = sumh4[r0*HD4+ob4], sh1 = sumh4[(r0+1)*HD4+ob4];
  float4 m0 = gru_out(z0, sh0, p0);
  float4 m1 = gru_out(z1, sh1, p1);
  ((float4*)msg)[(size_t)(n0+r0)*HD4 + ob4] = m0;
  ((float4*)msg)[(size_t)(n0+r0+1)*HD4 + ob4] = m1;
  __syncthreads();        // all pre-GEMM reads of sg done
  sg4[r0*HD4+ob4] = m0; sg4[(r0+1)*HD4+ob4] = m1;   // reuse sg as msg tile
  __syncthreads();

  // topo / stop head on msg
  const float4* btnl4 = (const float4*)b_topo_nl;
  const float4* wttopo4 = (const float4*)wt_topo;
  float4 q0 = btnl4[ob4], q1 = btnl4[ob4];
  for (int h=0;h<HD;++h){
    float a0 = sg[r0][h], a1 = sg[r0+1][h];
    float4 w = wttopo4[h*HD4+ob4];
    fma4(q0,a0,w); fma4(q1,a1,w);
  }
  float4 wt4v = ((const float4*)w_topo)[ob4];
  float th0 = dot4(relu4(q0), wt4v);
  float th1 = dot4(relu4(q1), wt4v);
  #pragma unroll
  for (int s=32;s>0;s>>=1){ th0 += __shfl_down(th0,s); th1 += __shfl_down(th1,s); }
  if (lane==0){ red[r0][oh]=th0; red[r0+1][oh]=th1; }
  __syncthreads();
  if (t<8) out_stop[n0+t] = red[t][0] + red[t][1] + b_topo[0];
}

// Sequential 64-step GRU + fused nuc head + hpn head + new_h write.
// Block = 8 rows for the whole scan (rows independent -> no grid sync needed).
__global__ __launch_bounds__(512) void scan_k(
    const int* __restrict__ nuc_idx,
    const float* __restrict__ msg,
    const float* __restrict__ graph_latent,
    const float* __restrict__ wt_lat,
    const float* __restrict__ wt_z, const float* __restrict__ wx_z, const float* __restrict__ bz,
    const float* __restrict__ wt_r, const float* __restrict__ wx_r, const float* __restrict__ br,
    const float* __restrict__ wt_h, const float* __restrict__ wx_h, const float* __restrict__ bh,
    const float* __restrict__ wt_nl, const float* __restrict__ b_nl,
    const float* __restrict__ w_nuc, const float* __restrict__ b_nuc,
    const float* __restrict__ wt_hpn_nl, const float* __restrict__ b_hpn_nl,
    const float* __restrict__ w_hpn, const float* __restrict__ b_hpn,
    float* __restrict__ out_newh, float* __restrict__ out_hpn, float* __restrict__ out_nuc)
{
  __shared__ float hl[8][HD];
  __shared__ float gld[8][HD];
  __shared__ float wns[NNUC][HD];
  __shared__ float gls[8][LATD];
  __shared__ float red[8][2][NNUC];

  const int t = threadIdx.x, lane = t&63, wv = t>>6;
  const int r0 = (wv>>1)<<1;
  const int oh = wv&1;
  const int ob4 = 64*oh + lane;
  const int n0 = blockIdx.x*8;

  float4* hl4 = (float4*)(&hl[0][0]);
  float4* gld4 = (float4*)(&gld[0][0]);
  float4* wns4 = (float4*)(&wns[0][0]);

  for (int idx=t; idx<8*HD4; idx+=512){
    hl4[idx] = ((const float4*)msg)[(size_t)n0*HD4 + idx];
  }
  for (int idx=t; idx<NNUC*HD4; idx+=512) wns4[idx] = ((const float4*)w_nuc)[idx];
  for (int idx=t; idx<8*(LATD/4); idx+=512)
    ((float4*)(&gls[0][0]))[idx] = ((const float4*)graph_latent)[(size_t)n0*(LATD/4) + idx];
  __syncthreads();

  // lat_part + b_nuc_nl, kept in registers
  const float4* bnl4 = (const float4*)b_nl;
  const float4* wtlat4 = (const float4*)wt_lat;
  float4 lp0 = bnl4[ob4], lp1 = bnl4[ob4];
  for (int q=0;q<LATD;++q){
    float4 w = wtlat4[q*HD4 + ob4];
    fma4(lp0, gls[r0][q], w);
    fma4(lp1, gls[r0+1][q], w);
  }

  const float4* bz4=(const float4*)bz; const float4* wxz4=(const float4*)wx_z; const float4* wtz4=(const float4*)wt_z;
  const float4* br4=(const float4*)br; const float4* wxr4=(const float4*)wx_r; const float4* wtr4=(const float4*)wt_r;
  const float4* bh4=(const float4*)bh; const float4* wxh4=(const float4*)wx_h; const float4* wth4=(const float4*)wt_h;
  const float4* wtnl4=(const float4*)wt_nl;

  for (int l=0;l<LSEQ;++l){
    const int c0 = nuc_idx[(size_t)(n0+r0)*LSEQ + l];
    const int c1 = nuc_idx[(size_t)(n0+r0+1)*LSEQ + l];
    // z and r gates (shared h reads)
    float4 z0 = bz4[ob4]; add4(z0, wxz4[c0*HD4+ob4]);
    float4 z1 = bz4[ob4]; add4(z1, wxz4[c1*HD4+ob4]);
    float4 rr0 = br4[ob4]; add4(rr0, wxr4[c0*HD4+ob4]);
    float4 rr1 = br4[ob4]; add4(rr1, wxr4[c1*HD4+ob4]);
    for (int h=0;h<HD;++h){
      float a0 = hl[r0][h], a1 = hl[r0+1][h];
      float4 wz = wtz4[h*HD4+ob4];
      float4 wr = wtr4[h*HD4+ob4];
      fma4(z0,a0,wz); fma4(z1,a1,wz);
      fma4(rr0,a0,wr); fma4(rr1,a1,wr);
    }
    z0 = sig4(z0); z1 = sig4(z1);
    float4 e0 = hl4[r0*HD4+ob4], e1 = hl4[(r0+1)*HD4+ob4];
    gld4[r0*HD4+ob4] = gate_mul(rr0, e0);
    gld4[(r0+1)*HD4+ob4] = gate_mul(rr1, e1);
    __syncthreads();
    // candidate
    float4 p0 = bh4[ob4]; add4(p0, wxh4[c0*HD4+ob4]);
    float4 p1 = bh4[ob4]; add4(p1, wxh4[c1*HD4+ob4]);
    for (int h=0;h<HD;++h){
      float a0 = gld[r0][h], a1 = gld[r0+1][h];
      float4 w = wth4[h*HD4+ob4];
      fma4(p0,a0,w); fma4(p1,a1,w);
    }
    float4 nh0 = gru_out(z0, e0, p0);
    float4 nh1 = gru_out(z1, e1, p1);
    __syncthreads();
    hl4[r0*HD4+ob4] = nh0;
    hl4[(r0+1)*HD4+ob4] = nh1;
    __syncthreads();
    // fused nuc head on the new hidden state
    float4 q0 = lp0, q1 = lp1;
    for (int h=0;h<HD;++h){
      float a0 = hl[r0][h], a1 = hl[r0+1][h];
      float4 w = wtnl4[h*HD4+ob4];
      fma4(q0,a0,w); fma4(q1,a1,w);
    }
    q0 = relu4(q0); q1 = relu4(q1);
    float lg0[NNUC], lg1[NNUC];
    #pragma unroll
    for (int j=0;j<NNUC;++j){
      float4 w = wns4[j*HD4 + ob4];
      lg0[j] = dot4(q0,w); lg1[j] = dot4(q1,w);
    }
    #pragma unroll
    for (int s=32;s>0;s>>=1){
      #pragma unroll
      for (int j=0;j<NNUC;++j){ lg0[j] += __shfl_down(lg0[j], s); lg1[j] += __shfl_down(lg1[j], s); }
    }
    if (lane==0){
      #pragma unroll
      for (int j=0;j<NNUC;++j){ red[r0][oh][j]=lg0[j]; red[r0+1][oh][j]=lg1[j]; }
    }
    __syncthreads();
    if (t < 8*NNUC){
      int r = t/NNUC, j = t - (t/NNUC)*NNUC;
      out_nuc[((size_t)(n0+r)*LSEQ + (size_t)l)*NNUC + j] = red[r][0][j] + red[r][1][j] + b_nuc[j];
    }
  }
  __syncthreads();

  // hpn head on final hidden state
  const float4* bhp4 = (const float4*)b_hpn_nl;
  const float4* wthp4 = (const float4*)wt_hpn_nl;
  float4 q0 = bhp4[ob4], q1 = bhp4[ob4];
  for (int h=0;h<HD;++h){
    float a0 = hl[r0][h], a1 = hl[r0+1][h];
    float4 w = wthp4[h*HD4+ob4];
    fma4(q0,a0,w); fma4(q1,a1,w);
  }
  q0 = relu4(q0); q1 = relu4(q1);
  float hg0[NHPN], hg1[NHPN];
  #pragma unroll
  for (int j=0;j<NHPN;++j){
    float4 w = ((const float4*)w_hpn)[j*HD4 + ob4];
    hg0[j] = dot4(q0,w); hg1[j] = dot4(q1,w);
  }
  #pragma unroll
  for (int s=32;s>0;s>>=1){
    #pragma unroll
    for (int j=0;j<NHPN;++j){ hg0[j]+=__shfl_down(hg0[j],s); hg1[j]+=__shfl_down(hg1[j],s); }
  }
  if (lane==0){
    #pragma unroll
    for (int j=0;j<NHPN;++j){ red[r0][oh][j]=hg0[j]; red[r0+1][oh][j]=hg1[j]; }
  }
  __syncthreads();
  if (t < 8*NHPN){
    int r=t/NHPN, j=t-(t/NHPN)*NHPN;
    out_hpn[(size_t)(n0+r)*NHPN + j] = red[r][0][j]+red[r][1][j]+b_hpn[j];
  }
  // write new_h
  for (int idx=t; idx<8*HD4; idx+=512){
    ((float4*)out_newh)[(size_t)n0*HD4 + idx] = hl4[idx];
  }
}

extern "C" void kernel_launch(void* const* d_in, const int* in_sizes, int n_in,
                              void* d_out, int out_size, void* d_ws, size_t ws_size,
                              hipStream_t stream){
  (void)in_sizes; (void)n_in; (void)out_size; (void)ws_size;
  const int*   hpn_idx      = (const int*)d_in[0];
  const int*   nuc_idx      = (const int*)d_in[1];
  const float* h_nei        = (const float*)d_in[2];
  const float* graph_latent = (const float*)d_in[3];
  const float* Wz_mp=(const float*)d_in[4];  const float* bz_mp=(const float*)d_in[5];
  const float* Wr_mp=(const float*)d_in[6];  const float* br_mp=(const float*)d_in[7];
  const float* Ur_mp=(const float*)d_in[8];
  const float* Wh_mp=(const float*)d_in[9];  const float* bh_mp=(const float*)d_in[10];
  const float* Wz_nuc=(const float*)d_in[11]; const float* bz_nuc=(const float*)d_in[12];
  const float* Wr_nuc=(const float*)d_in[13]; const float* br_nuc=(const float*)d_in[14];
  const float* Wh_nuc=(const float*)d_in[15]; const float* bh_nuc=(const float*)d_in[16];
  const float* W_hpn_nl=(const float*)d_in[17]; const float* b_hpn_nl=(const float*)d_in[18];
  const float* W_hpn=(const float*)d_in[19];  const float* b_hpn=(const float*)d_in[20];
  const float* W_nuc_nl=(const float*)d_in[21]; const float* b_nuc_nl=(const float*)d_in[22];
  const float* W_nuc=(const float*)d_in[23];  const float* b_nuc=(const float*)d_in[24];
  const float* W_topo_nl=(const float*)d_in[25]; const float* b_topo_nl=(const float*)d_in[26];
  const float* W_topo=(const float*)d_in[27]; const float* b_topo=(const float*)d_in[28];

  // workspace carve-up (floats); all sizes multiples of 4 for float4 access
  float* ws = (float*)d_ws;
  size_t off = 0;
  auto take = [&](size_t nfl){ float* p = ws + off; off += nfl; return p; };
  float* wt_z_mp   = take((size_t)HD*HD);
  float* wt_h_mp   = take((size_t)HD*HD);
  float* wt_ur     = take((size_t)HD*HD);
  float* wt_z_nuc  = take((size_t)HD*HD);
  float* wt_r_nuc  = take((size_t)HD*HD);
  float* wt_h_nuc  = take((size_t)HD*HD);
  float* wt_hpn    = take((size_t)HD*HD);
  float* wt_topo   = take((size_t)HD*HD);
  float* wt_nl_h   = take((size_t)HD*HD);
  float* wt_nl_lat = take((size_t)LATD*HD);
  float* wx_z_mp   = take((size_t)NHPN*HD);
  float* wx_h_mp   = take((size_t)NHPN*HD);
  float* wx_r_mp   = take((size_t)NHPN*HD);
  float* wx_z_nuc  = take((size_t)NNUC*HD);
  float* wx_r_nuc  = take((size_t)NNUC*HD);
  float* wx_h_nuc  = take((size_t)NNUC*HD);
  float* msg       = take((size_t)NROWS*HD);

  float* out       = (float*)d_out;
  float* out_newh  = out;
  float* out_hpn   = out + (size_t)NROWS*HD;
  float* out_nuc   = out_hpn + (size_t)NROWS*NHPN;
  float* out_stop  = out_nuc + (size_t)NROWS*LSEQ*NNUC;

  auto T = [&](const float* src, float* dst, int sc, int coff, int nh){
    int total = nh*HD;
    transpose_w<<<(total+255)/256, 256, 0, stream>>>(src, dst, sc, coff, nh);
  };
  T(Wz_mp,    wt_z_mp,   HD+NHPN, NHPN, HD);
  T(Wz_mp,    wx_z_mp,   HD+NHPN, 0,    NHPN);
  T(Wr_mp,    wx_r_mp,   NHPN,    0,    NHPN);
  T(Ur_mp,    wt_ur,     HD,      0,    HD);
  T(Wh_mp,    wt_h_mp,   HD+NHPN, NHPN, HD);
  T(Wh_mp,    wx_h_mp,   HD+NHPN, 0,    NHPN);
  T(Wz_nuc,   wt_z_nuc,  HD+NNUC, NNUC, HD);
  T(Wz_nuc,   wx_z_nuc,  HD+NNUC, 0,    NNUC);
  T(Wr_nuc,   wt_r_nuc,  HD+NNUC, NNUC, HD);
  T(Wr_nuc,   wx_r_nuc,  HD+NNUC, 0,    NNUC);
  T(Wh_nuc,   wt_h_nuc,  HD+NNUC, NNUC, HD);
  T(Wh_nuc,   wx_h_nuc,  HD+NNUC, 0,    NNUC);
  T(W_hpn_nl, wt_hpn,    HD,      0,    HD);
  T(W_topo_nl,wt_topo,   HD,      0,    HD);
  T(W_nuc_nl, wt_nl_h,   HD+LATD, 0,    HD);
  T(W_nuc_nl, wt_nl_lat, HD+LATD, HD,   LATD);

  graphgru_k<<<NROWS/8, 512, 0, stream>>>(
      hpn_idx, h_nei,
      wt_z_mp, wx_z_mp, bz_mp,
      wx_r_mp, br_mp, wt_ur,
      wt_h_mp, wx_h_mp, bh_mp,
      wt_topo, b_topo_nl, W_topo, b_topo,
      msg, out_stop);

  scan_k<<<NROWS/8, 512, 0, stream>>>(
      nuc_idx, msg, graph_latent, wt_nl_lat,
      wt_z_nuc, wx_z_nuc, bz_nuc,
      wt_r_nuc, wx_r_nuc, br_nuc,
      wt_h_nuc, wx_h_nuc, bh_nuc,
      wt_nl_h, b_nuc_nl, W_nuc, b_nuc,
      wt_hpn, b_hpn_nl, W_hpn, b_hpn,
      out_newh, out_hpn, out_nuc);
}

// Round 2
// 5132.544 us; speedup vs baseline: 4.6538x; 4.6538x over previous
//
#include <hip/hip_runtime.h>
#include <math.h>

#define NROWS 2048
#define KNEI  8
#define LSEQ  64
#define HD    512
#define HD4   128
#define LATD  128
#define NHPN  4
#define NNUC  5

typedef __attribute__((ext_vector_type(8))) short s8b;   // 8 bf16
typedef __attribute__((ext_vector_type(4))) float f4;    // MFMA acc

__device__ __forceinline__ float sigf(float x){ return 1.0f/(1.0f+__expf(-x)); }
__device__ __forceinline__ unsigned short f2bf(float x){
  union{float f; unsigned u;} v; v.f = x;
  unsigned r = (v.u + 0x7FFFu + ((v.u>>16)&1u)) >> 16;
  return (unsigned short)r;
}
__device__ __forceinline__ void fma4(float4& a, float s, float4 w){
  a.x = fmaf(s,w.x,a.x); a.y = fmaf(s,w.y,a.y); a.z = fmaf(s,w.z,a.z); a.w = fmaf(s,w.w,a.w);
}
__device__ __forceinline__ void add4(float4& a, float4 b){ a.x+=b.x; a.y+=b.y; a.z+=b.z; a.w+=b.w; }
__device__ __forceinline__ float4 sig4(float4 v){ return make_float4(sigf(v.x),sigf(v.y),sigf(v.z),sigf(v.w)); }
__device__ __forceinline__ float4 relu4(float4 v){ return make_float4(fmaxf(v.x,0.f),fmaxf(v.y,0.f),fmaxf(v.z,0.f),fmaxf(v.w,0.f)); }
__device__ __forceinline__ float dot4(float4 a, float4 b){ return a.x*b.x + a.y*b.y + a.z*b.z + a.w*b.w; }
__device__ __forceinline__ float4 gate_mul(float4 tv, float4 e){
  return make_float4(sigf(tv.x)*e.x, sigf(tv.y)*e.y, sigf(tv.z)*e.z, sigf(tv.w)*e.w);
}
__device__ __forceinline__ float4 gru_out(float4 z, float4 hprev, float4 pre){
  return make_float4((1.f-z.x)*hprev.x + z.x*tanhf(pre.x),
                     (1.f-z.y)*hprev.y + z.y*tanhf(pre.y),
                     (1.f-z.z)*hprev.z + z.z*tanhf(pre.z),
                     (1.f-z.w)*hprev.w + z.w*tanhf(pre.w));
}

// ---------------- prep kernels ----------------

// dst[h*HD + o] = src[o*src_cols + col_off + h]
__global__ void transpose_w(const float* __restrict__ src, float* __restrict__ dst,
                            int src_cols, int col_off, int nh){
  int idx = blockIdx.x*256 + threadIdx.x;
  if (idx >= nh*HD) return;
  int h = idx / HD, o = idx - h*HD;
  dst[idx] = src[o*src_cols + col_off + h];
}

// bf16 MFMA B-fragment layout: dst[tile*512 + l*8 + j] = W[n][col_off + k]
// tile = nt*16+kc ; n = nt*16+(l&15) ; k = kc*32 + (l>>4)*8 + j
__global__ void fragprep_k(const float* __restrict__ W, short* __restrict__ dst,
                           int src_cols, int col_off){
  int idx = blockIdx.x*256 + threadIdx.x;
  if (idx >= HD*HD) return;
  int j = idx&7, l = (idx>>3)&63, tile = idx>>9;
  int kc = tile&15, nt = tile>>4;
  int n = nt*16 + (l&15), k = kc*32 + (l>>4)*8 + j;
  dst[idx] = (short)f2bf(W[(size_t)n*src_cols + col_off + k]);
}

// wxb[c*HD + n] = W[n*src_cols + c] + b[n]   (x one-hot columns + bias folded)
__global__ void wxbprep_k(const float* __restrict__ W, const float* __restrict__ b,
                          float* __restrict__ dst, int src_cols){
  int idx = blockIdx.x*256 + threadIdx.x;
  if (idx >= NNUC*HD) return;
  int c = idx/HD, n = idx - c*HD;
  dst[idx] = W[(size_t)n*src_cols + c] + b[n];
}

// latp[n][o] = b_nl[o] + sum_q gl[n][q]*wtlat[q*HD+o]
__global__ __launch_bounds__(256) void latp_k(const float* __restrict__ gl, const float* __restrict__ wtlat,
                     const float* __restrict__ bnl, float* __restrict__ latp){
  __shared__ float gls[LATD];
  int n = blockIdx.x, t = threadIdx.x;
  if (t < LATD) gls[t] = gl[(size_t)n*LATD + t];
  __syncthreads();
  for (int o=t;o<HD;o+=256){
    float a = bnl[o];
    #pragma unroll 8
    for (int q=0;q<LATD;++q) a = fmaf(gls[q], wtlat[(size_t)q*HD+o], a);
    latp[(size_t)n*HD + o] = a;
  }
}

// ---------------- GraphGRU (unchanged fp32 path) ----------------
__global__ __launch_bounds__(512) void graphgru_k(
    const int* __restrict__ hpn_idx, const float* __restrict__ h_nei,
    const float* __restrict__ wt_z, const float* __restrict__ wx_z, const float* __restrict__ bz,
    const float* __restrict__ wx_r, const float* __restrict__ br,
    const float* __restrict__ wt_ur,
    const float* __restrict__ wt_h, const float* __restrict__ wx_h, const float* __restrict__ bh,
    const float* __restrict__ wt_topo, const float* __restrict__ b_topo_nl,
    const float* __restrict__ w_topo, const float* __restrict__ b_topo,
    float* __restrict__ msg, float* __restrict__ out_stop)
{
  __shared__ float sumh[8][HD];
  __shared__ float hk[8][HD];
  __shared__ float sg[8][HD];
  __shared__ float red[8][2];
  const int t = threadIdx.x, lane = t&63, wv = t>>6;
  const int r0 = (wv>>1)<<1;
  const int oh = wv&1;
  const int ob4 = 64*oh + lane;
  const int n0 = blockIdx.x*8;
  float4* sumh4 = (float4*)(&sumh[0][0]);
  float4* hk4   = (float4*)(&hk[0][0]);
  float4* sg4   = (float4*)(&sg[0][0]);
  const float4* hn4 = (const float4*)h_nei;

  for (int idx=t; idx<8*HD4; idx+=512){
    int r = idx>>7, c = idx&127;
    size_t base = ((size_t)(n0+r))*KNEI*HD4 + c;
    float4 s = hn4[base];
    #pragma unroll
    for (int k=1;k<KNEI;++k) add4(s, hn4[base + (size_t)k*HD4]);
    sumh4[idx] = s;
  }
  __syncthreads();

  const int hp0 = hpn_idx[n0+r0], hp1 = hpn_idx[n0+r0+1];
  const float4* bz4 = (const float4*)bz;
  const float4* wxz4 = (const float4*)wx_z;
  const float4* wtz4 = (const float4*)wt_z;
  float4 z0 = bz4[ob4]; add4(z0, wxz4[hp0*HD4 + ob4]);
  float4 z1 = bz4[ob4]; add4(z1, wxz4[hp1*HD4 + ob4]);
  for (int h=0;h<HD;++h){
    float a0 = sumh[r0][h], a1 = sumh[r0+1][h];
    float4 w = wtz4[h*HD4 + ob4];
    fma4(z0,a0,w); fma4(z1,a1,w);
  }
  z0 = sig4(z0); z1 = sig4(z1);

  const float4* br4 = (const float4*)br;
  const float4* wxr4 = (const float4*)wx_r;
  const float4* wtur4 = (const float4*)wt_ur;
  float4 rb0 = br4[ob4]; add4(rb0, wxr4[hp0*HD4 + ob4]);
  float4 rb1 = br4[ob4]; add4(rb1, wxr4[hp1*HD4 + ob4]);
  float4 sg0 = make_float4(0.f,0.f,0.f,0.f), sg1 = sg0;
  for (int k=0;k<KNEI;++k){
    __syncthreads();
    for (int idx=t; idx<8*HD4; idx+=512){
      int r = idx>>7, c = idx&127;
      hk4[idx] = hn4[((size_t)(n0+r)*KNEI + (size_t)k)*HD4 + c];
    }
    __syncthreads();
    float4 t0 = rb0, t1 = rb1;
    for (int h=0;h<HD;++h){
      float a0 = hk[r0][h], a1 = hk[r0+1][h];
      float4 w = wtur4[h*HD4 + ob4];
      fma4(t0,a0,w); fma4(t1,a1,w);
    }
    float4 e0 = hk4[r0*HD4 + ob4], e1 = hk4[(r0+1)*HD4 + ob4];
    add4(sg0, gate_mul(t0, e0));
    add4(sg1, gate_mul(t1, e1));
  }
  __syncthreads();
  sg4[r0*HD4+ob4] = sg0; sg4[(r0+1)*HD4+ob4] = sg1;
  __syncthreads();

  const float4* bh4 = (const float4*)bh;
  const float4* wxh4 = (const float4*)wx_h;
  const float4* wth4 = (const float4*)wt_h;
  float4 p0 = bh4[ob4]; add4(p0, wxh4[hp0*HD4+ob4]);
  float4 p1 = bh4[ob4]; add4(p1, wxh4[hp1*HD4+ob4]);
  for (int h=0;h<HD;++h){
    float a0 = sg[r0][h], a1 = sg[r0+1][h];
    float4 w = wth4[h*HD4+ob4];
    fma4(p0,a0,w); fma4(p1,a1,w);
  }
  float4 sh0 = sumh4[r0*HD4+ob4], sh1 = sumh4[(r0+1)*HD4+ob4];
  float4 m0 = gru_out(z0, sh0, p0);
  float4 m1 = gru_out(z1, sh1, p1);
  ((float4*)msg)[(size_t)(n0+r0)*HD4 + ob4] = m0;
  ((float4*)msg)[(size_t)(n0+r0+1)*HD4 + ob4] = m1;
  __syncthreads();
  sg4[r0*HD4+ob4] = m0; sg4[(r0+1)*HD4+ob4] = m1;
  __syncthreads();

  const float4* btnl4 = (const float4*)b_topo_nl;
  const float4* wttopo4 = (const float4*)wt_topo;
  float4 q0 = btnl4[ob4], q1 = btnl4[ob4];
  for (int h=0;h<HD;++h){
    float a0 = sg[r0][h], a1 = sg[r0+1][h];
    float4 w = wttopo4[h*HD4+ob4];
    fma4(q0,a0,w); fma4(q1,a1,w);
  }
  float4 wt4v = ((const float4*)w_topo)[ob4];
  float th0 = dot4(relu4(q0), wt4v);
  float th1 = dot4(relu4(q1), wt4v);
  #pragma unroll
  for (int s=32;s>0;s>>=1){ th0 += __shfl_down(th0,s); th1 += __shfl_down(th1,s); }
  if (lane==0){ red[r0][oh]=th0; red[r0+1][oh]=th1; }
  __syncthreads();
  if (t<8) out_stop[n0+t] = red[t][0] + red[t][1] + b_topo[0];
}

// ---------------- MFMA scan kernel ----------------
// 64 blocks x 512 threads (8 waves). Block owns 32 rows for all 64 steps.
// Per [32x512] GEMM: wave w -> ntiles 4w..4w+3, both mtiles. D-layout:
// row = mt*16 + (l>>4)*4 + q, col = (4w+i)*16 + (l&15).

__device__ __forceinline__ void gemm32(const short* __restrict__ frag,
                                       const short (*hBp)[HD+8],
                                       int w, int lm, int g, f4 acc[4][2])
{
  const s8b* B = (const s8b*)frag;
  const int l = g*16 + lm;
  #pragma unroll
  for (int i=0;i<4;++i){
    f4 z; z[0]=0.f; z[1]=0.f; z[2]=0.f; z[3]=0.f;
    acc[i][0]=z; acc[i][1]=z;
  }
  #pragma unroll
  for (int kc=0;kc<16;++kc){
    s8b a0 = *(const s8b*)&hBp[lm][kc*32 + g*8];
    s8b a1 = *(const s8b*)&hBp[16+lm][kc*32 + g*8];
    #pragma unroll
    for (int i=0;i<4;++i){
      s8b b = B[(size_t)(((4*w+i)*16 + kc)*64 + l)];
      acc[i][0] = __builtin_amdgcn_mfma_f32_16x16x32_bf16(a0, b, acc[i][0], 0,0,0);
      acc[i][1] = __builtin_amdgcn_mfma_f32_16x16x32_bf16(a1, b, acc[i][1], 0,0,0);
    }
  }
}

__global__ __launch_bounds__(512, 2) void scan_mfma_k(
    const int* __restrict__ nuc_idx,
    const float* __restrict__ msg,
    const short* __restrict__ fz, const short* __restrict__ fr,
    const short* __restrict__ fh, const short* __restrict__ fnuc,
    const short* __restrict__ fhpn,
    const float* __restrict__ wxbz, const float* __restrict__ wxbr, const float* __restrict__ wxbh,
    const float* __restrict__ latp,
    const float* __restrict__ w_nuc, const float* __restrict__ b_nuc,
    const float* __restrict__ b_hpn_nl, const float* __restrict__ w_hpn, const float* __restrict__ b_hpn,
    float* __restrict__ out_newh, float* __restrict__ out_hpn, float* __restrict__ out_nuc)
{
  __shared__ float hF[32][HD+4];      // fp32 master state
  __shared__ short hB[32][HD+8];      // bf16 A-operand (h or gated-h)
  __shared__ float wxb_s[3][NNUC][HD];
  __shared__ float wns[NNUC][HD];
  __shared__ int   codes[32];
  __shared__ float redbuf[8][32][NNUC];

  const int t = threadIdx.x, l = t&63, w = t>>6;
  const int lm = l&15, g = l>>4;
  const int n0 = blockIdx.x*32;

  for (int i=t;i<3*NNUC*HD;i+=512){
    int tb=i/(NNUC*HD), r2=i-tb*(NNUC*HD);
    const float* src = (tb==0)?wxbz:((tb==1)?wxbr:wxbh);
    wxb_s[tb][r2/HD][r2%HD] = src[r2];
  }
  for (int i=t;i<NNUC*HD;i+=512) wns[i/HD][i%HD] = w_nuc[i];
  for (int i=t;i<32*HD;i+=512){
    int r2=i>>9, c=i&511;
    float v = msg[(size_t)(n0+r2)*HD + c];
    hF[r2][c]=v; hB[r2][c]=(short)f2bf(v);
  }
  if (t<32) codes[t] = nuc_idx[(size_t)(n0+t)*LSEQ];
  __syncthreads();

  // step-invariant lat_part (+b_nuc_nl) at this lane's D positions
  float lp[4][2][4];
  #pragma unroll
  for (int i=0;i<4;++i){
    int col=(4*w+i)*16+lm;
    #pragma unroll
    for (int mt=0;mt<2;++mt)
      #pragma unroll
      for (int q=0;q<4;++q)
        lp[i][mt][q] = latp[(size_t)(n0+mt*16+g*4+q)*HD + col];
  }

  f4 zacc[4][2], cacc[4][2];

  for (int step=0; step<LSEQ; ++step){
    gemm32(fz, hB, w, lm, g, zacc);     // raw z pre-act (bias later)
    gemm32(fr, hB, w, lm, g, cacc);     // raw r pre-act
    // r-epilogue: gated h
    float ghv[4][2][4];
    #pragma unroll
    for (int i=0;i<4;++i){
      int col=(4*w+i)*16+lm;
      #pragma unroll
      for (int mt=0;mt<2;++mt)
        #pragma unroll
        for (int q=0;q<4;++q){
          int row = mt*16+g*4+q;
          float rv = sigf(cacc[i][mt][q] + wxb_s[1][codes[row]][col]);
          ghv[i][mt][q] = rv * hF[row][col];
        }
    }
    __syncthreads();                     // all hB reads (z,r GEMMs) done
    #pragma unroll
    for (int i=0;i<4;++i){
      int col=(4*w+i)*16+lm;
      #pragma unroll
      for (int mt=0;mt<2;++mt)
        #pragma unroll
        for (int q=0;q<4;++q) hB[mt*16+g*4+q][col] = (short)f2bf(ghv[i][mt][q]);
    }
    __syncthreads();                     // gh visible
    gemm32(fh, hB, w, lm, g, cacc);      // candidate pre-act
    float hnv[4][2][4];
    #pragma unroll
    for (int i=0;i<4;++i){
      int col=(4*w+i)*16+lm;
      #pragma unroll
      for (int mt=0;mt<2;++mt)
        #pragma unroll
        for (int q=0;q<4;++q){
          int row = mt*16+g*4+q;
          int c = codes[row];
          float pre = tanhf(cacc[i][mt][q] + wxb_s[2][c][col]);
          float zv  = sigf(zacc[i][mt][q] + wxb_s[0][c][col]);
          hnv[i][mt][q] = (1.f-zv)*hF[row][col] + zv*pre;
        }
    }
    __syncthreads();                     // all hB(gh)/hF reads done
    #pragma unroll
    for (int i=0;i<4;++i){
      int col=(4*w+i)*16+lm;
      #pragma unroll
      for (int mt=0;mt<2;++mt)
        #pragma unroll
        for (int q=0;q<4;++q){
          int row = mt*16+g*4+q;
          hF[row][col] = hnv[i][mt][q];
          hB[row][col] = (short)f2bf(hnv[i][mt][q]);
        }
    }
    if (t<32 && step+1<LSEQ) codes[t] = nuc_idx[(size_t)(n0+t)*LSEQ + step+1];
    __syncthreads();                     // h(t+1) visible
    // nuc head on h(t+1)
    gemm32(fnuc, hB, w, lm, g, cacc);
    float p[2][4][NNUC];
    #pragma unroll
    for (int mt=0;mt<2;++mt)
      #pragma unroll
      for (int q=0;q<4;++q)
        #pragma unroll
        for (int j=0;j<NNUC;++j) p[mt][q][j]=0.f;
    #pragma unroll
    for (int i=0;i<4;++i){
      int col=(4*w+i)*16+lm;
      #pragma unroll
      for (int mt=0;mt<2;++mt)
        #pragma unroll
        for (int q=0;q<4;++q){
          float hid = fmaxf(cacc[i][mt][q] + lp[i][mt][q], 0.f);
          #pragma unroll
          for (int j=0;j<NNUC;++j) p[mt][q][j] = fmaf(hid, wns[j][col], p[mt][q][j]);
        }
    }
    #pragma unroll
    for (int s=8;s>=1;s>>=1){
      #pragma unroll
      for (int mt=0;mt<2;++mt)
        #pragma unroll
        for (int q=0;q<4;++q)
          #pragma unroll
          for (int j=0;j<NNUC;++j) p[mt][q][j] += __shfl_xor(p[mt][q][j], s);
    }
    if (lm==0){
      #pragma unroll
      for (int mt=0;mt<2;++mt)
        #pragma unroll
        for (int q=0;q<4;++q)
          #pragma unroll
          for (int j=0;j<NNUC;++j) redbuf[w][mt*16+g*4+q][j] = p[mt][q][j];
    }
    __syncthreads();
    if (t < 32*NNUC){
      int r2 = t/NNUC, j = t - r2*NNUC;
      float s = 0.f;
      #pragma unroll
      for (int ww=0;ww<8;++ww) s += redbuf[ww][r2][j];
      out_nuc[((size_t)(n0+r2)*LSEQ + step)*NNUC + j] = s + b_nuc[j];
    }
  }
  __syncthreads();

  // hpn head on h(64) (hB still holds it)
  gemm32(fhpn, hB, w, lm, g, cacc);
  float ph[2][4][NHPN];
  #pragma unroll
  for (int mt=0;mt<2;++mt)
    #pragma unroll
    for (int q=0;q<4;++q)
      #pragma unroll
      for (int j=0;j<NHPN;++j) ph[mt][q][j]=0.f;
  #pragma unroll
  for (int i=0;i<4;++i){
    int col=(4*w+i)*16+lm;
    float bnl = b_hpn_nl[col];
    #pragma unroll
    for (int mt=0;mt<2;++mt)
      #pragma unroll
      for (int q=0;q<4;++q){
        float hid = fmaxf(cacc[i][mt][q] + bnl, 0.f);
        #pragma unroll
        for (int j=0;j<NHPN;++j) ph[mt][q][j] = fmaf(hid, w_hpn[(size_t)j*HD + col], ph[mt][q][j]);
      }
  }
  #pragma unroll
  for (int s=8;s>=1;s>>=1){
    #pragma unroll
    for (int mt=0;mt<2;++mt)
      #pragma unroll
      for (int q=0;q<4;++q)
        #pragma unroll
        for (int j=0;j<NHPN;++j) ph[mt][q][j] += __shfl_xor(ph[mt][q][j], s);
  }
  if (lm==0){
    #pragma unroll
    for (int mt=0;mt<2;++mt)
      #pragma unroll
      for (int q=0;q<4;++q)
        #pragma unroll
        for (int j=0;j<NHPN;++j) redbuf[w][mt*16+g*4+q][j] = ph[mt][q][j];
  }
  __syncthreads();
  if (t < 32*NHPN){
    int r2 = t/NHPN, j = t - r2*NHPN;
    float s = 0.f;
    #pragma unroll
    for (int ww=0;ww<8;++ww) s += redbuf[ww][r2][j];
    out_hpn[(size_t)(n0+r2)*NHPN + j] = s + b_hpn[j];
  }
  for (int i=t;i<32*HD;i+=512){
    int r2=i>>9, c=i&511;
    out_newh[(size_t)(n0+r2)*HD + c] = hF[r2][c];
  }
}

// ---------------- host ----------------
extern "C" void kernel_launch(void* const* d_in, const int* in_sizes, int n_in,
                              void* d_out, int out_size, void* d_ws, size_t ws_size,
                              hipStream_t stream){
  (void)in_sizes; (void)n_in; (void)out_size; (void)ws_size;
  const int*   hpn_idx      = (const int*)d_in[0];
  const int*   nuc_idx      = (const int*)d_in[1];
  const float* h_nei        = (const float*)d_in[2];
  const float* graph_latent = (const float*)d_in[3];
  const float* Wz_mp=(const float*)d_in[4];  const float* bz_mp=(const float*)d_in[5];
  const float* Wr_mp=(const float*)d_in[6];  const float* br_mp=(const float*)d_in[7];
  const float* Ur_mp=(const float*)d_in[8];
  const float* Wh_mp=(const float*)d_in[9];  const float* bh_mp=(const float*)d_in[10];
  const float* Wz_nuc=(const float*)d_in[11]; const float* bz_nuc=(const float*)d_in[12];
  const float* Wr_nuc=(const float*)d_in[13]; const float* br_nuc=(const float*)d_in[14];
  const float* Wh_nuc=(const float*)d_in[15]; const float* bh_nuc=(const float*)d_in[16];
  const float* W_hpn_nl=(const float*)d_in[17]; const float* b_hpn_nl=(const float*)d_in[18];
  const float* W_hpn=(const float*)d_in[19];  const float* b_hpn=(const float*)d_in[20];
  const float* W_nuc_nl=(const float*)d_in[21]; const float* b_nuc_nl=(const float*)d_in[22];
  const float* W_nuc=(const float*)d_in[23];  const float* b_nuc=(const float*)d_in[24];
  const float* W_topo_nl=(const float*)d_in[25]; const float* b_topo_nl=(const float*)d_in[26];
  const float* W_topo=(const float*)d_in[27]; const float* b_topo=(const float*)d_in[28];

  float* ws = (float*)d_ws;
  size_t off = 0;
  auto take = [&](size_t nfl){ float* p = ws + off; off += nfl; return p; };
  // graphgru fp32 transposed weights
  float* wt_z_mp   = take((size_t)HD*HD);
  float* wt_ur     = take((size_t)HD*HD);
  float* wt_h_mp   = take((size_t)HD*HD);
  float* wt_topo   = take((size_t)HD*HD);
  float* wt_nl_lat = take((size_t)LATD*HD);
  float* wx_z_mp   = take((size_t)NHPN*HD);
  float* wx_h_mp   = take((size_t)NHPN*HD);
  float* wx_r_mp   = take((size_t)NHPN*HD);
  // scan bf16 fragment weights (each HD*HD shorts = HD*HD/2 floats)
  short* fz   = (short*)take((size_t)HD*HD/2);
  short* fr   = (short*)take((size_t)HD*HD/2);
  short* fh   = (short*)take((size_t)HD*HD/2);
  short* fnuc = (short*)take((size_t)HD*HD/2);
  short* fhpn = (short*)take((size_t)HD*HD/2);
  // bias tables
  float* wxbz = take((size_t)NNUC*HD);
  float* wxbr = take((size_t)NNUC*HD);
  float* wxbh = take((size_t)NNUC*HD);
  float* latp = take((size_t)NROWS*HD);
  float* msg  = take((size_t)NROWS*HD);

  float* out       = (float*)d_out;
  float* out_newh  = out;
  float* out_hpn   = out + (size_t)NROWS*HD;
  float* out_nuc   = out_hpn + (size_t)NROWS*NHPN;
  float* out_stop  = out_nuc + (size_t)NROWS*LSEQ*NNUC;

  auto T = [&](const float* src, float* dst, int sc, int coff, int nh){
    int total = nh*HD;
    transpose_w<<<(total+255)/256, 256, 0, stream>>>(src, dst, sc, coff, nh);
  };
  T(Wz_mp,    wt_z_mp,   HD+NHPN, NHPN, HD);
  T(Wz_mp,    wx_z_mp,   HD+NHPN, 0,    NHPN);
  T(Wr_mp,    wx_r_mp,   NHPN,    0,    NHPN);
  T(Ur_mp,    wt_ur,     HD,      0,    HD);
  T(Wh_mp,    wt_h_mp,   HD+NHPN, NHPN, HD);
  T(Wh_mp,    wx_h_mp,   HD+NHPN, 0,    NHPN);
  T(W_topo_nl,wt_topo,   HD,      0,    HD);
  T(W_nuc_nl, wt_nl_lat, HD+LATD, HD,   LATD);

  const int FB = (HD*HD+255)/256;
  fragprep_k<<<FB,256,0,stream>>>(Wz_nuc,   fz,   HD+NNUC, NNUC);
  fragprep_k<<<FB,256,0,stream>>>(Wr_nuc,   fr,   HD+NNUC, NNUC);
  fragprep_k<<<FB,256,0,stream>>>(Wh_nuc,   fh,   HD+NNUC, NNUC);
  fragprep_k<<<FB,256,0,stream>>>(W_nuc_nl, fnuc, HD+LATD, 0);
  fragprep_k<<<FB,256,0,stream>>>(W_hpn_nl, fhpn, HD,      0);

  const int WB = (NNUC*HD+255)/256;
  wxbprep_k<<<WB,256,0,stream>>>(Wz_nuc, bz_nuc, wxbz, HD+NNUC);
  wxbprep_k<<<WB,256,0,stream>>>(Wr_nuc, br_nuc, wxbr, HD+NNUC);
  wxbprep_k<<<WB,256,0,stream>>>(Wh_nuc, bh_nuc, wxbh, HD+NNUC);

  latp_k<<<NROWS,256,0,stream>>>(graph_latent, wt_nl_lat, b_nuc_nl, latp);

  graphgru_k<<<NROWS/8, 512, 0, stream>>>(
      hpn_idx, h_nei,
      wt_z_mp, wx_z_mp, bz_mp,
      wx_r_mp, br_mp, wt_ur,
      wt_h_mp, wx_h_mp, bh_mp,
      wt_topo, b_topo_nl, W_topo, b_topo,
      msg, out_stop);

  scan_mfma_k<<<NROWS/32, 512, 0, stream>>>(
      nuc_idx, msg,
      fz, fr, fh, fnuc, fhpn,
      wxbz, wxbr, wxbh, latp,
      W_nuc, b_nuc, b_hpn_nl, W_hpn, b_hpn,
      out_newh, out_hpn, out_nuc);
}